// Round 2
// baseline (7167.692 us; speedup 1.0000x reference)
//
#include <hip/hip_runtime.h>
#include <cstdint>
#include <cstddef>

#define B 128
#define T 64
#define IDIM 128
#define E 256
#define H 512

__device__ __forceinline__ float waveReduceSum(float v) {
    for (int off = 32; off > 0; off >>= 1) v += __shfl_xor(v, off, 64);
    return v;
}

__device__ __forceinline__ float fast_tanh(float v) {
    float a = fabsf(v);
    float e = __expf(-2.f * a);
    float r = (1.f - e) * __builtin_amdgcn_rcpf(1.f + e);
    return copysignf(r, v);
}

__device__ __forceinline__ float sigmoidf_(float x) {
    return 1.0f / (1.0f + __expf(-x));
}

// ---------------------------------------------------------------------------
// x[b,t,i] = dot(input[b,t,i,:], news_W) + news_b   (HBM-bound, 1 GB read)
__global__ __launch_bounds__(256) void news_kernel(
    const float* __restrict__ in, const float* __restrict__ nW,
    const float* __restrict__ nb, float* __restrict__ x)
{
    int out_idx = blockIdx.x * 4 + (threadIdx.x >> 6);
    int lane = threadIdx.x & 63;
    const float4* src = (const float4*)(in + (size_t)out_idx * E);
    float4 a = src[lane];
    float4 wv = ((const float4*)nW)[lane];
    float s = a.x * wv.x + a.y * wv.y + a.z * wv.z + a.w * wv.w;
    s = waveReduceSum(s);
    if (lane == 0) x[out_idx] = s + nb[0];
}

// ---------------------------------------------------------------------------
// z2[b,i,s] = sum_t x[b,t,i] * A2[s,t] + b2[s]   layout [B,I,T]
__global__ __launch_bounds__(64) void z2_kernel(
    const float* __restrict__ x, const float* __restrict__ A2,
    const float* __restrict__ b2, float* __restrict__ z2)
{
    int b = blockIdx.x >> 7;
    int i = blockIdx.x & 127;
    int s = threadIdx.x;
    __shared__ float xs[T];
    xs[s] = x[((size_t)b * T + s) * IDIM + i];
    __syncthreads();
    float acc = b2[s];
    const float* arow = A2 + s * T;
#pragma unroll 8
    for (int tt = 0; tt < T; ++tt) acc += xs[tt] * arow[tt];
    z2[((size_t)b * IDIM + i) * T + s] = acc;
}

// ---------------------------------------------------------------------------
// Persistent scan kernel. Grid MUST be 256 blocks x 256 threads.
// LDS ~120 KB => exactly 1 block/CU => all 256 co-resident on 256 CUs.
//
// Pool layout (floats):
#define OFF_W   0        // Wlds[640][32]  (20480)
#define OFF_A   20480    // Atile[2][128][32] (8192); buf1 aliased as red4; buf0 as glds
#define OFF_HC  28672    // hc[1024]
#define OFF_Z1  29696    // z1s[64]
#define OFF_RED 29760    // red[128]
#define OFF_B   29888    // bias[32]
#define POOL_F  29920

__device__ __forceinline__ void grid_sync(int* cnt, int target) {
    __syncthreads();
    if (threadIdx.x == 0) {
        __threadfence();
        __hip_atomic_fetch_add(cnt, 1, __ATOMIC_RELEASE, __HIP_MEMORY_SCOPE_AGENT);
        int spins = 0;
        while (__hip_atomic_load(cnt, __ATOMIC_ACQUIRE, __HIP_MEMORY_SCOPE_AGENT) < target) {
            __builtin_amdgcn_s_sleep(1);
            if (++spins > (1 << 18)) break;  // anti-deadlock: fail visibly, don't hang
        }
    }
    __syncthreads();
    __threadfence();  // acquire: don't serve stale L1/L2 after the barrier
}

// stage: src rows [32 b][ld] chunk of 128 k  ->  Atile buf [128 kk][32 b] (transposed)
__device__ __forceinline__ void stage_load(const float* src, int ld, float4 v[4],
                                           int sb, int st8) {
    const float* row = src + (size_t)sb * ld;
#pragma unroll
    for (int q = 0; q < 4; ++q)
        v[q] = *(const float4*)(row + (st8 + 8 * q) * 4);
}

__device__ __forceinline__ void stage_write(float* dst, float4 v[4], int sb, int st8) {
#pragma unroll
    for (int q = 0; q < 4; ++q) {
        int kk = (st8 + 8 * q) * 4;
        dst[(kk + 0) * 32 + sb] = v[q].x;
        dst[(kk + 1) * 32 + sb] = v[q].y;
        dst[(kk + 2) * 32 + sb] = v[q].z;
        dst[(kk + 3) * 32 + sb] = v[q].w;
    }
}

#define FMA4(A, S) { (A).x += (S)*av.x; (A).y += (S)*av.y; (A).z += (S)*av.z; (A).w += (S)*av.w; }

__device__ __forceinline__ void compute_chunk(const float* Wl, const float* At,
                                              int kabs0, int wave, int jg, int bg,
                                              float4 acc[4]) {
    int kk0 = wave * 32;
#pragma unroll 8
    for (int kk = kk0; kk < kk0 + 32; ++kk) {
        float4 wv = *(const float4*)(Wl + (size_t)(kabs0 + kk) * 32 + jg * 4);
        float4 av = *(const float4*)(At + kk * 32 + bg * 4);
        FMA4(acc[0], wv.x); FMA4(acc[1], wv.y);
        FMA4(acc[2], wv.z); FMA4(acc[3], wv.w);
    }
}

__global__ __launch_bounds__(256, 1) void scan_kernel(
    const float* __restrict__ x, const float* __restrict__ z2,
    const float* __restrict__ A1, const float* __restrict__ b1,
    const float* __restrict__ a3w,
    const float* __restrict__ Wih, const float* __restrict__ Whh,
    const float* __restrict__ bih, const float* __restrict__ bhh,
    float* __restrict__ wbuf, float* __restrict__ hpp, float* __restrict__ cpp,
    int* __restrict__ cnt, float* __restrict__ out)
{
    __shared__ float pool[POOL_F];
    float* Wlds  = pool + OFF_W;
    float* Atile = pool + OFF_A;
    float* hcs   = pool + OFF_HC;
    float* z1s   = pool + OFF_Z1;
    float* redl  = pool + OFF_RED;
    float* blds  = pool + OFF_B;

    const int tid  = threadIdx.x;
    const int bid  = blockIdx.x;
    const int lane = tid & 63, wave = tid >> 6;
    const int jg = lane & 7, bg = lane >> 3;      // compute tile coords
    const int sb = tid >> 3, st8 = tid & 7;       // staging coords
    const int bq = bid >> 6, ns = bid & 63;       // 4 batch-quarters x 64 n-slices
    const int b0 = bq * 32, n0 = ns * 8;
    const bool is_attn = (bid < B);

    // one-time: load weight slice (columns j = g*512 + n0 + nn, 4 gates x 8 n)
    for (int idx = tid; idx < 640 * 32; idx += 256) {
        int jj = idx / 640, k = idx - jj * 640;   // consecutive k => coalesced
        int j = (jj >> 3) * 512 + n0 + (jj & 7);
        Wlds[k * 32 + jj] = (k < 128) ? Wih[(size_t)j * 128 + k]
                                      : Whh[(size_t)j * 512 + (k - 128)];
    }
    if (tid < 32) {
        int j = (tid >> 3) * 512 + n0 + (tid & 7);
        blds[tid] = bih[j] + bhh[j];
    }

    int target = 0;
    for (int t = 0; t < T; ++t) {
        const float* hin = hpp + (t & 1) * (B * H);
        const float* cin = cpp + (t & 1) * (B * H);
        float* hout = hpp + ((t + 1) & 1) * (B * H);
        float* cout = cpp + ((t + 1) & 1) * (B * H);

        // ---------------- phase A: attention (blocks 0..127, batch = bid) ----
        if (is_attn) {
            int b = bid;
            for (int k2 = tid; k2 < H; k2 += 256) {
                hcs[k2]     = hin[b * H + k2];
                hcs[H + k2] = cin[b * H + k2];
            }
            __syncthreads();
            const float4* hc4 = (const float4*)hcs;
            for (int r = 0; r < 16; ++r) {
                int tt = r * 4 + wave;
                const float4* row = (const float4*)(A1 + (size_t)tt * (2 * H));
                float p = 0.f;
#pragma unroll
                for (int q = 0; q < 4; ++q) {
                    float4 avv = row[q * 64 + lane];
                    float4 hvv = hc4[q * 64 + lane];
                    p += avv.x * hvv.x + avv.y * hvv.y + avv.z * hvv.z + avv.w * hvv.w;
                }
                p = waveReduceSum(p);
                if (lane == 0) z1s[tt] = p + b1[tt];
            }
            __syncthreads();
            int i = tid >> 1, half = tid & 1;
            const float* z2r = z2 + ((size_t)b * IDIM + i) * T + half * 32;
            const float* z1p = z1s + half * 32;
            const float* a3p = a3w + half * 32;
            float accz = 0.f;
#pragma unroll
            for (int q = 0; q < 8; ++q) {
                float4 zv  = *(const float4*)(z2r + q * 4);
                float4 z1v = *(const float4*)(z1p + q * 4);
                float4 a3v = *(const float4*)(a3p + q * 4);
                accz += fast_tanh(z1v.x + zv.x) * a3v.x
                      + fast_tanh(z1v.y + zv.y) * a3v.y
                      + fast_tanh(z1v.z + zv.z) * a3v.z
                      + fast_tanh(z1v.w + zv.w) * a3v.w;
            }
            accz += __shfl_xor(accz, 1, 64);
            if (!half) redl[i] = accz;
            __syncthreads();
            if (wave == 0) {
                float v0 = redl[lane], v1 = redl[lane + 64];
                float m = fmaxf(v0, v1);
                for (int off = 32; off > 0; off >>= 1)
                    m = fmaxf(m, __shfl_xor(m, off, 64));
                float e0 = __expf(v0 - m), e1 = __expf(v1 - m);
                float ssum = waveReduceSum(e0 + e1);
                float inv = 1.0f / ssum;
                const float* xt = x + ((size_t)b * T + t) * IDIM;
                wbuf[b * IDIM + lane]      = e0 * inv * xt[lane];
                wbuf[b * IDIM + lane + 64] = e1 * inv * xt[lane + 64];
            }
        }

        // ---------------- phase B part 1: h-chunks (k = 128..640) -----------
        float4 acc[4];
        acc[0] = acc[1] = acc[2] = acc[3] = make_float4(0.f, 0.f, 0.f, 0.f);
        {
            float4 v[4];
            stage_load(hin + b0 * H, H, v, sb, st8);
            stage_write(Atile, v, sb, st8);   // buf0
            __syncthreads();
            for (int c = 0; c < 4; ++c) {
                float4 vn[4];
                if (c < 3) stage_load(hin + b0 * H + (c + 1) * 128, H, vn, sb, st8);
                compute_chunk(Wlds, Atile + (c & 1) * 4096, 128 + c * 128,
                              wave, jg, bg, acc);
                if (c < 3) stage_write(Atile + ((c + 1) & 1) * 4096, vn, sb, st8);
                __syncthreads();
            }
        }

        target += 256;
        grid_sync(cnt, target);               // w_t ready

        // ---------------- phase B part 2: w-chunk (k = 0..128) --------------
        {
            float4 v[4];
            stage_load(wbuf + b0 * IDIM, IDIM, v, sb, st8);
            stage_write(Atile, v, sb, st8);   // buf0 (last read: chunk 2, synced)
            __syncthreads();
            compute_chunk(Wlds, Atile, 0, wave, jg, bg, acc);
        }

        // ---------------- cross-wave k-reduction + update -------------------
        float* red4 = Atile + 4096;           // buf1 (free: last read chunk 3)
#pragma unroll
        for (int ji = 0; ji < 4; ++ji)
            *(float4*)(red4 + wave * 1024 + (jg * 4 + ji) * 32 + bg * 4) = acc[ji];
        __syncthreads();

        float* glds = Atile;                  // buf0 (free after sync above)
        {
            int jj = tid >> 3, bq8 = tid & 7;
            int off = jj * 32 + bq8 * 4;
            float4 g0 = *(const float4*)(red4 + off);
            float4 g1 = *(const float4*)(red4 + 1024 + off);
            float4 g2 = *(const float4*)(red4 + 2048 + off);
            float4 g3 = *(const float4*)(red4 + 3072 + off);
            float bias = blds[jj];
            float4 gv;
            gv.x = g0.x + g1.x + g2.x + g3.x + bias;
            gv.y = g0.y + g1.y + g2.y + g3.y + bias;
            gv.z = g0.z + g1.z + g2.z + g3.z + bias;
            gv.w = g0.w + g1.w + g2.w + g3.w + bias;
            *(float4*)(glds + off) = gv;
        }
        __syncthreads();
        {
            int ub = tid >> 3, un = tid & 7;  // 32 b x 8 n
            float ig = glds[(0 * 8 + un) * 32 + ub];
            float fg = glds[(1 * 8 + un) * 32 + ub];
            float gg = glds[(2 * 8 + un) * 32 + ub];
            float og = glds[(3 * 8 + un) * 32 + ub];
            int gb = b0 + ub, gn = n0 + un;
            float cold = cin[gb * H + gn];
            float cnew = sigmoidf_(fg) * cold + sigmoidf_(ig) * tanhf(gg);
            float hnew = sigmoidf_(og) * tanhf(cnew);
            cout[gb * H + gn] = cnew;
            hout[gb * H + gn] = hnew;
            out[((size_t)gb * T + t) * H + gn] = hnew;
        }

        target += 256;
        grid_sync(cnt, target);               // h_{t+1}, c_{t+1} ready
    }
}

// ---------------------------------------------------------------------------
extern "C" void kernel_launch(void* const* d_in, const int* in_sizes, int n_in,
                              void* d_out, int out_size, void* d_ws, size_t ws_size,
                              hipStream_t stream)
{
    const float* input  = (const float*)d_in[0];
    const float* news_W = (const float*)d_in[1];
    const float* news_b = (const float*)d_in[2];
    const float* A1     = (const float*)d_in[3];
    const float* b1     = (const float*)d_in[4];
    const float* A2     = (const float*)d_in[5];
    const float* b2     = (const float*)d_in[6];
    const float* a3w    = (const float*)d_in[7];
    // d_in[8] = attn3_b: softmax-invariant, unused
    const float* Wih    = (const float*)d_in[9];
    const float* Whh    = (const float*)d_in[10];
    const float* bih    = (const float*)d_in[11];
    const float* bhh    = (const float*)d_in[12];
    float* out = (float*)d_out;

    char* ws = (char*)d_ws;
    size_t off = 0;
    auto alloc = [&](size_t nelem) {
        float* p = (float*)(ws + off);
        off += ((nelem * 4 + 255) / 256) * 256;
        return p;
    };
    float* x    = alloc((size_t)B * T * IDIM);   // 4 MB
    float* z2   = alloc((size_t)B * IDIM * T);   // 4 MB
    float* wbuf = alloc((size_t)B * IDIM);       // 64 KB
    float* hpp  = alloc((size_t)2 * B * H);      // ping-pong h
    float* cpp  = alloc((size_t)2 * B * H);      // ping-pong c
    int*   cnt  = (int*)alloc(64);

    hipMemsetAsync(hpp, 0, (size_t)2 * B * H * 4, stream);
    hipMemsetAsync(cpp, 0, (size_t)2 * B * H * 4, stream);
    hipMemsetAsync(cnt, 0, 256, stream);

    news_kernel<<<B * T * IDIM / 4, 256, 0, stream>>>(input, news_W, news_b, x);
    z2_kernel<<<B * IDIM, 64, 0, stream>>>(x, A2, b2, z2);
    scan_kernel<<<256, 256, 0, stream>>>(x, z2, A1, b1, a3w, Wih, Whh, bih, bhh,
                                         wbuf, hpp, cpp, cnt, out);
}

// Round 3
// 2274.846 us; speedup vs baseline: 3.1508x; 3.1508x over previous
//
#include <hip/hip_runtime.h>
#include <cstdint>
#include <cstddef>

#define B 128
#define T 64
#define IDIM 128
#define E 256
#define H 512

__device__ __forceinline__ float waveReduceSum(float v) {
    for (int off = 32; off > 0; off >>= 1) v += __shfl_xor(v, off, 64);
    return v;
}

__device__ __forceinline__ float fast_tanh(float v) {
    float a = fabsf(v);
    float e = __expf(-2.f * a);
    float r = (1.f - e) * __builtin_amdgcn_rcpf(1.f + e);
    return copysignf(r, v);
}

__device__ __forceinline__ float sigmoidf_(float x) {
    return 1.0f / (1.0f + __expf(-x));
}

// Coherent (cache-bypassing) accessors for cross-block shared state.
// Relaxed atomics at agent scope emit sc1-routed global ops: no L2 flush,
// served at the memory-side coherence point. This is the whole fix.
__device__ __forceinline__ float aload(const float* p) {
    return __hip_atomic_load(p, __ATOMIC_RELAXED, __HIP_MEMORY_SCOPE_AGENT);
}
__device__ __forceinline__ void astore(float* p, float v) {
    __hip_atomic_store(p, v, __ATOMIC_RELAXED, __HIP_MEMORY_SCOPE_AGENT);
}

// ---------------------------------------------------------------------------
// x[b,t,i] = dot(input[b,t,i,:], news_W) + news_b   (HBM-bound, 1 GB read)
__global__ __launch_bounds__(256) void news_kernel(
    const float* __restrict__ in, const float* __restrict__ nW,
    const float* __restrict__ nb, float* __restrict__ x)
{
    int out_idx = blockIdx.x * 4 + (threadIdx.x >> 6);
    int lane = threadIdx.x & 63;
    const float4* src = (const float4*)(in + (size_t)out_idx * E);
    float4 a = src[lane];
    float4 wv = ((const float4*)nW)[lane];
    float s = a.x * wv.x + a.y * wv.y + a.z * wv.z + a.w * wv.w;
    s = waveReduceSum(s);
    if (lane == 0) x[out_idx] = s + nb[0];
}

// ---------------------------------------------------------------------------
// z2[b,i,s] = sum_t x[b,t,i] * A2[s,t] + b2[s]   layout [B,I,T]
__global__ __launch_bounds__(64) void z2_kernel(
    const float* __restrict__ x, const float* __restrict__ A2,
    const float* __restrict__ b2, float* __restrict__ z2)
{
    int b = blockIdx.x >> 7;
    int i = blockIdx.x & 127;
    int s = threadIdx.x;
    __shared__ float xs[T];
    xs[s] = x[((size_t)b * T + s) * IDIM + i];
    __syncthreads();
    float acc = b2[s];
    const float* arow = A2 + s * T;
#pragma unroll 8
    for (int tt = 0; tt < T; ++tt) acc += xs[tt] * arow[tt];
    z2[((size_t)b * IDIM + i) * T + s] = acc;
}

// ---------------------------------------------------------------------------
// Persistent scan kernel. Grid MUST be 256 blocks x 256 threads.
// LDS ~120 KB => exactly 1 block/CU => all 256 co-resident on 256 CUs.
#define OFF_W   0        // Wlds[640][32]  (20480)
#define OFF_A   20480    // Atile[2][128][32] (8192); buf1 aliased as red4; buf0 as glds
#define OFF_HC  28672    // hc[1024]
#define OFF_Z1  29696    // z1s[64]
#define OFF_RED 29760    // red[128]
#define OFF_B   29888    // bias[32]
#define POOL_F  29920

// Cheap grid barrier: relaxed RMW + relaxed polling. No cache maintenance.
// Data ordering: __syncthreads() drains each wave's vmcnt before s_barrier;
// explicit waitcnt in thread 0 covers its own wave before the arrive.
__device__ __forceinline__ void grid_sync(int* cnt, int target) {
    __syncthreads();
    if (threadIdx.x == 0) {
        asm volatile("s_waitcnt vmcnt(0) lgkmcnt(0)" ::: "memory");
        __hip_atomic_fetch_add(cnt, 1, __ATOMIC_RELAXED, __HIP_MEMORY_SCOPE_AGENT);
        int spins = 0;
        while (__hip_atomic_load(cnt, __ATOMIC_RELAXED, __HIP_MEMORY_SCOPE_AGENT) < target) {
            __builtin_amdgcn_s_sleep(2);
            if (++spins > (1 << 18)) break;  // anti-deadlock: fail visibly, don't hang
        }
    }
    __syncthreads();
}

// stage: coherent-load rows [32 b][ld] chunk of 128 k (scalar sc1 loads)
__device__ __forceinline__ void stage_load_a(const float* src, int ld, float4 v[4],
                                             int sb, int st8) {
    const float* row = src + (size_t)sb * ld + st8 * 4;
#pragma unroll
    for (int q = 0; q < 4; ++q) {
        const float* p = row + 32 * q;
        v[q].x = aload(p + 0);
        v[q].y = aload(p + 1);
        v[q].z = aload(p + 2);
        v[q].w = aload(p + 3);
    }
}

__device__ __forceinline__ void stage_write(float* dst, float4 v[4], int sb, int st8) {
#pragma unroll
    for (int q = 0; q < 4; ++q) {
        int kk = (st8 + 8 * q) * 4;
        dst[(kk + 0) * 32 + sb] = v[q].x;
        dst[(kk + 1) * 32 + sb] = v[q].y;
        dst[(kk + 2) * 32 + sb] = v[q].z;
        dst[(kk + 3) * 32 + sb] = v[q].w;
    }
}

#define FMA4(A, S) { (A).x += (S)*av.x; (A).y += (S)*av.y; (A).z += (S)*av.z; (A).w += (S)*av.w; }

__device__ __forceinline__ void compute_chunk(const float* Wl, const float* At,
                                              int kabs0, int wave, int jg, int bg,
                                              float4 acc[4]) {
    int kk0 = wave * 32;
#pragma unroll 8
    for (int kk = kk0; kk < kk0 + 32; ++kk) {
        float4 wv = *(const float4*)(Wl + (size_t)(kabs0 + kk) * 32 + jg * 4);
        float4 av = *(const float4*)(At + kk * 32 + bg * 4);
        FMA4(acc[0], wv.x); FMA4(acc[1], wv.y);
        FMA4(acc[2], wv.z); FMA4(acc[3], wv.w);
    }
}

__global__ __launch_bounds__(256, 1) void scan_kernel(
    const float* __restrict__ x, const float* __restrict__ z2,
    const float* __restrict__ A1, const float* __restrict__ b1,
    const float* __restrict__ a3w,
    const float* __restrict__ Wih, const float* __restrict__ Whh,
    const float* __restrict__ bih, const float* __restrict__ bhh,
    float* __restrict__ wbuf, float* __restrict__ hpp, float* __restrict__ cpp,
    int* __restrict__ cnt, float* __restrict__ out)
{
    __shared__ float pool[POOL_F];
    float* Wlds  = pool + OFF_W;
    float* Atile = pool + OFF_A;
    float* hcs   = pool + OFF_HC;
    float* z1s   = pool + OFF_Z1;
    float* redl  = pool + OFF_RED;
    float* blds  = pool + OFF_B;

    const int tid  = threadIdx.x;
    const int bid  = blockIdx.x;
    const int lane = tid & 63, wave = tid >> 6;
    const int jg = lane & 7, bg = lane >> 3;      // compute tile coords
    const int sb = tid >> 3, st8 = tid & 7;       // staging coords
    const int bq = bid >> 6, ns = bid & 63;       // 4 batch-quarters x 64 n-slices
    const int b0 = bq * 32, n0 = ns * 8;
    const bool is_attn = (bid < B);

    // one-time: load weight slice (columns j = g*512 + n0 + nn, 4 gates x 8 n)
    for (int idx = tid; idx < 640 * 32; idx += 256) {
        int jj = idx / 640, k = idx - jj * 640;   // consecutive k => coalesced
        int j = (jj >> 3) * 512 + n0 + (jj & 7);
        Wlds[k * 32 + jj] = (k < 128) ? Wih[(size_t)j * 128 + k]
                                      : Whh[(size_t)j * 512 + (k - 128)];
    }
    if (tid < 32) {
        int j = (tid >> 3) * 512 + n0 + (tid & 7);
        blds[tid] = bih[j] + bhh[j];
    }

    int target = 0;
    for (int t = 0; t < T; ++t) {
        const float* hin = hpp + (t & 1) * (B * H);
        const float* cin = cpp + (t & 1) * (B * H);
        float* hout = hpp + ((t + 1) & 1) * (B * H);
        float* cout = cpp + ((t + 1) & 1) * (B * H);

        // ---------------- phase A: attention (blocks 0..127, batch = bid) ----
        if (is_attn) {
            int b = bid;
            for (int k2 = tid; k2 < H; k2 += 256) {
                hcs[k2]     = aload(hin + b * H + k2);
                hcs[H + k2] = aload(cin + b * H + k2);
            }
            __syncthreads();
            const float4* hc4 = (const float4*)hcs;
            for (int r = 0; r < 16; ++r) {
                int tt = r * 4 + wave;
                const float4* row = (const float4*)(A1 + (size_t)tt * (2 * H));
                float p = 0.f;
#pragma unroll
                for (int q = 0; q < 4; ++q) {
                    float4 avv = row[q * 64 + lane];
                    float4 hvv = hc4[q * 64 + lane];
                    p += avv.x * hvv.x + avv.y * hvv.y + avv.z * hvv.z + avv.w * hvv.w;
                }
                p = waveReduceSum(p);
                if (lane == 0) z1s[tt] = p + b1[tt];
            }
            __syncthreads();
            int i = tid >> 1, half = tid & 1;
            const float* z2r = z2 + ((size_t)b * IDIM + i) * T + half * 32;
            const float* z1p = z1s + half * 32;
            const float* a3p = a3w + half * 32;
            float accz = 0.f;
#pragma unroll
            for (int q = 0; q < 8; ++q) {
                float4 zv  = *(const float4*)(z2r + q * 4);
                float4 z1v = *(const float4*)(z1p + q * 4);
                float4 a3v = *(const float4*)(a3p + q * 4);
                accz += fast_tanh(z1v.x + zv.x) * a3v.x
                      + fast_tanh(z1v.y + zv.y) * a3v.y
                      + fast_tanh(z1v.z + zv.z) * a3v.z
                      + fast_tanh(z1v.w + zv.w) * a3v.w;
            }
            accz += __shfl_xor(accz, 1, 64);
            if (!half) redl[i] = accz;
            __syncthreads();
            if (wave == 0) {
                float v0 = redl[lane], v1 = redl[lane + 64];
                float m = fmaxf(v0, v1);
                for (int off = 32; off > 0; off >>= 1)
                    m = fmaxf(m, __shfl_xor(m, off, 64));
                float e0 = __expf(v0 - m), e1 = __expf(v1 - m);
                float ssum = waveReduceSum(e0 + e1);
                float inv = 1.0f / ssum;
                const float* xt = x + ((size_t)b * T + t) * IDIM;
                astore(wbuf + b * IDIM + lane,      e0 * inv * xt[lane]);
                astore(wbuf + b * IDIM + lane + 64, e1 * inv * xt[lane + 64]);
            }
        }

        // ---------------- phase B part 1: h-chunks (k = 128..640) -----------
        float4 acc[4];
        acc[0] = acc[1] = acc[2] = acc[3] = make_float4(0.f, 0.f, 0.f, 0.f);
        {
            float4 v[4];
            stage_load_a(hin + b0 * H, H, v, sb, st8);
            stage_write(Atile, v, sb, st8);   // buf0
            __syncthreads();
            for (int c = 0; c < 4; ++c) {
                float4 vn[4];
                if (c < 3) stage_load_a(hin + b0 * H + (c + 1) * 128, H, vn, sb, st8);
                compute_chunk(Wlds, Atile + (c & 1) * 4096, 128 + c * 128,
                              wave, jg, bg, acc);
                if (c < 3) stage_write(Atile + ((c + 1) & 1) * 4096, vn, sb, st8);
                __syncthreads();
            }
        }

        target += 256;
        grid_sync(cnt, target);               // w_t ready

        // ---------------- phase B part 2: w-chunk (k = 0..128) --------------
        {
            float4 v[4];
            stage_load_a(wbuf + b0 * IDIM, IDIM, v, sb, st8);
            stage_write(Atile, v, sb, st8);   // buf0 (last read: chunk 2, synced)
            __syncthreads();
            compute_chunk(Wlds, Atile, 0, wave, jg, bg, acc);
        }

        // ---------------- cross-wave k-reduction + update -------------------
        float* red4 = Atile + 4096;           // buf1 (free: last read chunk 3)
#pragma unroll
        for (int ji = 0; ji < 4; ++ji)
            *(float4*)(red4 + wave * 1024 + (jg * 4 + ji) * 32 + bg * 4) = acc[ji];
        __syncthreads();

        float* glds = Atile;                  // buf0 (free after sync above)
        {
            int jj = tid >> 3, bq8 = tid & 7;
            int off = jj * 32 + bq8 * 4;
            float4 g0 = *(const float4*)(red4 + off);
            float4 g1 = *(const float4*)(red4 + 1024 + off);
            float4 g2 = *(const float4*)(red4 + 2048 + off);
            float4 g3 = *(const float4*)(red4 + 3072 + off);
            float bias = blds[jj];
            float4 gv;
            gv.x = g0.x + g1.x + g2.x + g3.x + bias;
            gv.y = g0.y + g1.y + g2.y + g3.y + bias;
            gv.z = g0.z + g1.z + g2.z + g3.z + bias;
            gv.w = g0.w + g1.w + g2.w + g3.w + bias;
            *(float4*)(glds + off) = gv;
        }
        __syncthreads();
        {
            int ub = tid >> 3, un = tid & 7;  // 32 b x 8 n
            float ig = glds[(0 * 8 + un) * 32 + ub];
            float fg = glds[(1 * 8 + un) * 32 + ub];
            float gg = glds[(2 * 8 + un) * 32 + ub];
            float og = glds[(3 * 8 + un) * 32 + ub];
            int gb = b0 + ub, gn = n0 + un;
            float cold = aload(cin + gb * H + gn);
            float cnew = sigmoidf_(fg) * cold + sigmoidf_(ig) * tanhf(gg);
            float hnew = sigmoidf_(og) * tanhf(cnew);
            astore(cout + gb * H + gn, cnew);
            astore(hout + gb * H + gn, hnew);
            out[((size_t)gb * T + t) * H + gn] = hnew;
        }

        target += 256;
        grid_sync(cnt, target);               // h_{t+1}, c_{t+1} ready
    }
}

// ---------------------------------------------------------------------------
extern "C" void kernel_launch(void* const* d_in, const int* in_sizes, int n_in,
                              void* d_out, int out_size, void* d_ws, size_t ws_size,
                              hipStream_t stream)
{
    const float* input  = (const float*)d_in[0];
    const float* news_W = (const float*)d_in[1];
    const float* news_b = (const float*)d_in[2];
    const float* A1     = (const float*)d_in[3];
    const float* b1     = (const float*)d_in[4];
    const float* A2     = (const float*)d_in[5];
    const float* b2     = (const float*)d_in[6];
    const float* a3w    = (const float*)d_in[7];
    // d_in[8] = attn3_b: softmax-invariant, unused
    const float* Wih    = (const float*)d_in[9];
    const float* Whh    = (const float*)d_in[10];
    const float* bih    = (const float*)d_in[11];
    const float* bhh    = (const float*)d_in[12];
    float* out = (float*)d_out;

    char* ws = (char*)d_ws;
    size_t off = 0;
    auto alloc = [&](size_t nelem) {
        float* p = (float*)(ws + off);
        off += ((nelem * 4 + 255) / 256) * 256;
        return p;
    };
    float* x    = alloc((size_t)B * T * IDIM);   // 4 MB
    float* z2   = alloc((size_t)B * IDIM * T);   // 4 MB
    float* wbuf = alloc((size_t)B * IDIM);       // 64 KB
    float* hpp  = alloc((size_t)2 * B * H);      // ping-pong h
    float* cpp  = alloc((size_t)2 * B * H);      // ping-pong c
    int*   cnt  = (int*)alloc(64);

    hipMemsetAsync(hpp, 0, (size_t)2 * B * H * 4, stream);
    hipMemsetAsync(cpp, 0, (size_t)2 * B * H * 4, stream);
    hipMemsetAsync(cnt, 0, 256, stream);

    news_kernel<<<B * T * IDIM / 4, 256, 0, stream>>>(input, news_W, news_b, x);
    z2_kernel<<<B * IDIM, 64, 0, stream>>>(x, A2, b2, z2);
    scan_kernel<<<256, 256, 0, stream>>>(x, z2, A1, b1, a3w, Wih, Whh, bih, bhh,
                                         wbuf, hpp, cpp, cnt, out);
}

// Round 4
// 1412.411 us; speedup vs baseline: 5.0748x; 1.6106x over previous
//
#include <hip/hip_runtime.h>
#include <cstdint>
#include <cstddef>

#define B 128
#define T 64
#define IDIM 128
#define E 256
#define H 512
#define NT 512

#define AT_STRIDE 34
#define AT_CH (128 * AT_STRIDE)   // 4352 floats per 128-k chunk

// LDS pool offsets (floats)
#define OFF_W   0                       // Wlds[640][32] = 20480
#define OFF_A   20480                   // At4[4][AT_CH] = 17408
#define OFF_HC  (OFF_A + 4 * AT_CH)     // hc[1024]
#define OFF_Z1  (OFF_HC + 1024)        // z1s[64]
#define OFF_RED (OFF_Z1 + 64)          // red[128]
#define OFF_BI  (OFF_RED + 128)        // bias[32]
#define POOL_F  (OFF_BI + 32)          // 39136 floats = 156544 B (<160K)

__device__ __forceinline__ float waveReduceSum(float v) {
    for (int off = 32; off > 0; off >>= 1) v += __shfl_xor(v, off, 64);
    return v;
}

__device__ __forceinline__ float fast_tanh(float v) {
    float a = fabsf(v);
    float e = __expf(-2.f * a);
    float r = (1.f - e) * __builtin_amdgcn_rcpf(1.f + e);
    return copysignf(r, v);
}

__device__ __forceinline__ float sigmoidf_(float x) {
    return 1.0f / (1.0f + __expf(-x));
}

// Coherent scalar accessors (bypass stale L1/L2; served at IF$).
__device__ __forceinline__ float aload(const float* p) {
    return __hip_atomic_load(p, __ATOMIC_RELAXED, __HIP_MEMORY_SCOPE_AGENT);
}
__device__ __forceinline__ void astore(float* p, float v) {
    __hip_atomic_store(p, v, __ATOMIC_RELAXED, __HIP_MEMORY_SCOPE_AGENT);
}

// Coherent 16B load (async — must waitvm0() before using the result).
__device__ __forceinline__ float4 cload4(const float* p) {
    float4 v;
    asm volatile("global_load_dwordx4 %0, %1, off sc0 sc1" : "=v"(v) : "v"(p));
    return v;
}
__device__ __forceinline__ void waitvm0() {
    asm volatile("s_waitcnt vmcnt(0)" ::: "memory");
}

// ---------------------------------------------------------------------------
__global__ __launch_bounds__(256) void news_kernel(
    const float* __restrict__ in, const float* __restrict__ nW,
    const float* __restrict__ nb, float* __restrict__ x)
{
    int out_idx = blockIdx.x * 4 + (threadIdx.x >> 6);
    int lane = threadIdx.x & 63;
    const float4* src = (const float4*)(in + (size_t)out_idx * E);
    float4 a = src[lane];
    float4 wv = ((const float4*)nW)[lane];
    float s = a.x * wv.x + a.y * wv.y + a.z * wv.z + a.w * wv.w;
    s = waveReduceSum(s);
    if (lane == 0) x[out_idx] = s + nb[0];
}

// ---------------------------------------------------------------------------
__global__ __launch_bounds__(64) void z2_kernel(
    const float* __restrict__ x, const float* __restrict__ A2,
    const float* __restrict__ b2, float* __restrict__ z2)
{
    int b = blockIdx.x >> 7;
    int i = blockIdx.x & 127;
    int s = threadIdx.x;
    __shared__ float xs[T];
    xs[s] = x[((size_t)b * T + s) * IDIM + i];
    __syncthreads();
    float acc = b2[s];
    const float* arow = A2 + s * T;
#pragma unroll 8
    for (int tt = 0; tt < T; ++tt) acc += xs[tt] * arow[tt];
    z2[((size_t)b * IDIM + i) * T + s] = acc;
}

// ---------------------------------------------------------------------------
// Per-quarter two-level barrier: 64 blocks = 8 groups x 8.
// sub[q*8+g] at cnt[(q*8+g)*32]; root[q] at cnt[1024 + q*32].
__device__ __forceinline__ void qsync(int* cnt, int q, int ns, int ph) {
    __syncthreads();
    if (threadIdx.x == 0) {
        asm volatile("s_waitcnt vmcnt(0) lgkmcnt(0)" ::: "memory");
        int* subp  = cnt + (q * 8 + (ns >> 3)) * 32;
        int* rootp = cnt + 1024 + q * 32;
        int old = __hip_atomic_fetch_add(subp, 1, __ATOMIC_RELAXED,
                                         __HIP_MEMORY_SCOPE_AGENT);
        if (old == ph * 8 - 1)
            __hip_atomic_fetch_add(rootp, 1, __ATOMIC_RELAXED,
                                   __HIP_MEMORY_SCOPE_AGENT);
        int spins = 0;
        while (__hip_atomic_load(rootp, __ATOMIC_RELAXED,
                                 __HIP_MEMORY_SCOPE_AGENT) < ph * 8) {
            __builtin_amdgcn_s_sleep(1);
            if (++spins > (1 << 20)) break;  // fail visibly, never hang
        }
    }
    __syncthreads();
}

#define FMA4(A, S) { (A).x += (S)*av.x; (A).y += (S)*av.y; (A).z += (S)*av.z; (A).w += (S)*av.w; }

// ---------------------------------------------------------------------------
// Persistent scan. 256 blocks x 512 threads; block bid = q*64 + ns:
// quarter q (batches q*32..+32), n-slice ns (8 cols per gate). 4 independent
// 64-block sub-problems; all sync is per-quarter.
__global__ __launch_bounds__(NT, 1) void scan_kernel(
    const float* __restrict__ x, const float* __restrict__ z2,
    const float* __restrict__ A1, const float* __restrict__ b1,
    const float* __restrict__ a3w,
    const float* __restrict__ Wih, const float* __restrict__ Whh,
    const float* __restrict__ bih, const float* __restrict__ bhh,
    float* __restrict__ wbuf, float* __restrict__ hpp, float* __restrict__ cpp,
    int* __restrict__ cnt, float* __restrict__ out)
{
    __shared__ float pool[POOL_F];
    float* Wlds = pool + OFF_W;
    float* At4  = pool + OFF_A;
    float* hcs  = pool + OFF_HC;
    float* z1s  = pool + OFF_Z1;
    float* redl = pool + OFF_RED;
    float* blds = pool + OFF_BI;

    const int tid  = threadIdx.x;
    const int bid  = blockIdx.x;
    const int lane = tid & 63, wave = tid >> 6;
    const int q = bid >> 6, ns = bid & 63;
    const int b0 = q * 32, n0 = ns * 8;
    const bool is_attn = ((ns & 1) == 0);
    const int ab = b0 + (ns >> 1);             // attn batch (intra-quarter)
    const int jg = lane & 7, bg = lane >> 3;   // compute tile coords
    const int half = tid >> 8;                 // h-staging: 2 halves x 2 chunks
    const int sbh = (tid & 255) >> 3;          // batch row 0..31
    const int st8 = tid & 7;

    // one-time: weight slice (cols j = g*512 + n0 + nn; 4 gates x 8 n)
    for (int idx = tid; idx < 640 * 32; idx += NT) {
        int jj = idx / 640, k = idx - jj * 640;
        int j = (jj >> 3) * 512 + n0 + (jj & 7);
        Wlds[k * 32 + jj] = (k < 128) ? Wih[(size_t)j * 128 + k]
                                      : Whh[(size_t)j * 512 + (k - 128)];
    }
    if (tid < 32) {
        int j = (tid >> 3) * 512 + n0 + (tid & 7);
        blds[tid] = bih[j] + bhh[j];
    }

    int ph = 0;
    for (int t = 0; t < T; ++t) {
        const float* hin = hpp + (t & 1) * (B * H);
        const float* cin = cpp + (t & 1) * (B * H);
        float* hout = hpp + ((t + 1) & 1) * (B * H);
        float* cout = cpp + ((t + 1) & 1) * (B * H);

        // -------- issue coherent h-tile prefetch (latency hides under attn)
        float4 hv[8];
        {
            const float* hrow = hin + (size_t)(b0 + sbh) * H + half * 256;
#pragma unroll
            for (int cc = 0; cc < 2; ++cc)
#pragma unroll
                for (int qq = 0; qq < 4; ++qq)
                    hv[cc * 4 + qq] = cload4(hrow + cc * 128 + (st8 + 8 * qq) * 4);
        }

        // -------- phase A: attention (even-ns blocks, batch ab) -------------
        if (is_attn) {
            hcs[tid]     = aload(hin + (size_t)ab * H + tid);
            hcs[H + tid] = aload(cin + (size_t)ab * H + tid);
            __syncthreads();
            const float4* hc4 = (const float4*)hcs;
            for (int r = 0; r < 8; ++r) {
                int tt = r * 8 + wave;
                const float4* row = (const float4*)(A1 + (size_t)tt * (2 * H));
                float p = 0.f;
#pragma unroll
                for (int qq = 0; qq < 4; ++qq) {
                    float4 avv = row[qq * 64 + lane];
                    float4 hvv = hc4[qq * 64 + lane];
                    p += avv.x * hvv.x + avv.y * hvv.y + avv.z * hvv.z + avv.w * hvv.w;
                }
                p = waveReduceSum(p);
                if (lane == 0) z1s[tt] = p + b1[tt];
            }
            __syncthreads();
            int i = tid >> 2, qt = tid & 3;
            const float* z2r = z2 + ((size_t)ab * IDIM + i) * T + qt * 16;
            const float* z1p = z1s + qt * 16;
            const float* a3p = a3w + qt * 16;
            float accz = 0.f;
#pragma unroll
            for (int qq = 0; qq < 4; ++qq) {
                float4 zv  = *(const float4*)(z2r + qq * 4);
                float4 z1v = *(const float4*)(z1p + qq * 4);
                float4 a3v = *(const float4*)(a3p + qq * 4);
                accz += fast_tanh(z1v.x + zv.x) * a3v.x
                      + fast_tanh(z1v.y + zv.y) * a3v.y
                      + fast_tanh(z1v.z + zv.z) * a3v.z
                      + fast_tanh(z1v.w + zv.w) * a3v.w;
            }
            accz += __shfl_xor(accz, 1, 64);
            accz += __shfl_xor(accz, 2, 64);
            if (qt == 0) redl[i] = accz;
            __syncthreads();
            if (wave == 0) {
                float v0 = redl[lane], v1 = redl[lane + 64];
                float m = fmaxf(v0, v1);
                for (int off = 32; off > 0; off >>= 1)
                    m = fmaxf(m, __shfl_xor(m, off, 64));
                float e0 = __expf(v0 - m), e1 = __expf(v1 - m);
                float inv = 1.0f / waveReduceSum(e0 + e1);
                const float* xt = x + ((size_t)ab * T + t) * IDIM;
                astore(wbuf + ab * IDIM + lane,      e0 * inv * xt[lane]);
                astore(wbuf + ab * IDIM + lane + 64, e1 * inv * xt[lane + 64]);
            }
        }

        // -------- stage h-tile into LDS (transposed, stride-34) -------------
        waitvm0();
        {
#pragma unroll
            for (int cc = 0; cc < 2; ++cc)
#pragma unroll
                for (int qq = 0; qq < 4; ++qq) {
                    float4 v = hv[cc * 4 + qq];
                    float* d = At4 + (half * 2 + cc) * AT_CH
                             + ((st8 + 8 * qq) * 4) * AT_STRIDE + sbh;
                    d[0] = v.x; d[AT_STRIDE] = v.y;
                    d[2 * AT_STRIDE] = v.z; d[3 * AT_STRIDE] = v.w;
                }
        }
        __syncthreads();

        // -------- B1: h-part GEMM, wave k-split (64 kk each of 512) ---------
        float4 acc[4];
        acc[0] = acc[1] = acc[2] = acc[3] = make_float4(0.f, 0.f, 0.f, 0.f);
        {
            const float* Ab = At4 + (wave >> 1) * AT_CH
                            + ((wave & 1) * 64) * AT_STRIDE + bg * 4;
            const float* Wb = Wlds + (size_t)(128 + wave * 64) * 32 + jg * 4;
#pragma unroll 8
            for (int i = 0; i < 64; ++i) {
                float4 wv = *(const float4*)(Wb + i * 32);
                float2 a01 = *(const float2*)(Ab + i * AT_STRIDE);
                float2 a23 = *(const float2*)(Ab + i * AT_STRIDE + 2);
                float4 av = make_float4(a01.x, a01.y, a23.x, a23.y);
                FMA4(acc[0], wv.x); FMA4(acc[1], wv.y);
                FMA4(acc[2], wv.z); FMA4(acc[3], wv.w);
            }
        }

        qsync(cnt, q, ns, ++ph);              // wbuf ready (quarter-local)

        // -------- stage w-tile, B2: w-part GEMM (16 kk each of 128) ---------
        {
            const float* wrow = wbuf + (size_t)(b0 + (tid >> 4)) * IDIM;
            float4 w0 = cload4(wrow + (tid & 15) * 4);
            float4 w1 = cload4(wrow + ((tid & 15) + 16) * 4);
            waitvm0();
            int sbw = tid >> 4, st16 = tid & 15;
            float* d0 = At4 + (st16 * 4) * AT_STRIDE + sbw;
            d0[0] = w0.x; d0[AT_STRIDE] = w0.y;
            d0[2 * AT_STRIDE] = w0.z; d0[3 * AT_STRIDE] = w0.w;
            float* d1 = At4 + ((st16 + 16) * 4) * AT_STRIDE + sbw;
            d1[0] = w1.x; d1[AT_STRIDE] = w1.y;
            d1[2 * AT_STRIDE] = w1.z; d1[3 * AT_STRIDE] = w1.w;
        }
        __syncthreads();
        {
            const float* Ab = At4 + (wave * 16) * AT_STRIDE + bg * 4;
            const float* Wb = Wlds + (size_t)(wave * 16) * 32 + jg * 4;
#pragma unroll
            for (int i = 0; i < 16; ++i) {
                float4 wv = *(const float4*)(Wb + i * 32);
                float2 a01 = *(const float2*)(Ab + i * AT_STRIDE);
                float2 a23 = *(const float2*)(Ab + i * AT_STRIDE + 2);
                float4 av = make_float4(a01.x, a01.y, a23.x, a23.y);
                FMA4(acc[0], wv.x); FMA4(acc[1], wv.y);
                FMA4(acc[2], wv.z); FMA4(acc[3], wv.w);
            }
        }

        // -------- 8-way cross-wave k-reduction + LSTM update ----------------
        float* red4 = At4 + AT_CH;            // chunks 1-2 region (dead)
#pragma unroll
        for (int ji = 0; ji < 4; ++ji)
            *(float4*)(red4 + wave * 1024 + (jg * 4 + ji) * 32 + bg * 4) = acc[ji];
        __syncthreads();

        float* glds = At4;                    // w-tile region (dead after B2)
        if (tid < 256) {
            int jj = tid >> 3, b8 = tid & 7;
            int off = jj * 32 + b8 * 4;
            float4 s = make_float4(0.f, 0.f, 0.f, 0.f);
#pragma unroll
            for (int w = 0; w < 8; ++w) {
                float4 g = *(const float4*)(red4 + w * 1024 + off);
                s.x += g.x; s.y += g.y; s.z += g.z; s.w += g.w;
            }
            float bias = blds[jj];
            s.x += bias; s.y += bias; s.z += bias; s.w += bias;
            *(float4*)(glds + off) = s;
        }
        __syncthreads();
        if (tid < 256) {
            int ub = tid >> 3, un = tid & 7;
            float ig = glds[(0 * 8 + un) * 32 + ub];
            float fg = glds[(1 * 8 + un) * 32 + ub];
            float gg = glds[(2 * 8 + un) * 32 + ub];
            float og = glds[(3 * 8 + un) * 32 + ub];
            int gb = b0 + ub, gn = n0 + un;
            float cold = aload(cin + (size_t)gb * H + gn);
            float cnew = sigmoidf_(fg) * cold + sigmoidf_(ig) * tanhf(gg);
            float hnew = sigmoidf_(og) * tanhf(cnew);
            astore(cout + (size_t)gb * H + gn, cnew);
            astore(hout + (size_t)gb * H + gn, hnew);
            out[((size_t)gb * T + t) * H + gn] = hnew;
        }

        qsync(cnt, q, ns, ++ph);              // h_{t+1}, c_{t+1} ready
    }
}

// ---------------------------------------------------------------------------
extern "C" void kernel_launch(void* const* d_in, const int* in_sizes, int n_in,
                              void* d_out, int out_size, void* d_ws, size_t ws_size,
                              hipStream_t stream)
{
    const float* input  = (const float*)d_in[0];
    const float* news_W = (const float*)d_in[1];
    const float* news_b = (const float*)d_in[2];
    const float* A1     = (const float*)d_in[3];
    const float* b1     = (const float*)d_in[4];
    const float* A2     = (const float*)d_in[5];
    const float* b2     = (const float*)d_in[6];
    const float* a3w    = (const float*)d_in[7];
    // d_in[8] = attn3_b: softmax-invariant, unused
    const float* Wih    = (const float*)d_in[9];
    const float* Whh    = (const float*)d_in[10];
    const float* bih    = (const float*)d_in[11];
    const float* bhh    = (const float*)d_in[12];
    float* out = (float*)d_out;

    char* ws = (char*)d_ws;
    size_t off = 0;
    auto alloc = [&](size_t nelem) {
        float* p = (float*)(ws + off);
        off += ((nelem * 4 + 255) / 256) * 256;
        return p;
    };
    float* x    = alloc((size_t)B * T * IDIM);   // 4 MB
    float* z2   = alloc((size_t)B * IDIM * T);   // 4 MB
    float* wbuf = alloc((size_t)B * IDIM);       // 64 KB
    float* hpp  = alloc((size_t)2 * B * H);      // ping-pong h
    float* cpp  = alloc((size_t)2 * B * H);      // ping-pong c
    int*   cnt  = (int*)alloc(2048);             // barrier counters

    hipMemsetAsync(hpp, 0, (size_t)2 * B * H * 4, stream);
    hipMemsetAsync(cpp, 0, (size_t)2 * B * H * 4, stream);
    hipMemsetAsync(cnt, 0, 2048 * 4, stream);

    news_kernel<<<B * T * IDIM / 4, 256, 0, stream>>>(input, news_W, news_b, x);
    z2_kernel<<<B * IDIM, 64, 0, stream>>>(x, A2, b2, z2);
    scan_kernel<<<256, NT, 0, stream>>>(x, z2, A1, b1, a3w, Wih, Whh, bih, bhh,
                                        wbuf, hpp, cpp, cnt, out);
}

// Round 5
// 1378.859 us; speedup vs baseline: 5.1983x; 1.0243x over previous
//
#include <hip/hip_runtime.h>
#include <cstdint>
#include <cstddef>

#define B 128
#define T 64
#define IDIM 128
#define E 256
#define H 512
#define NT 512

#define AT_STRIDE 34
#define AT_CH (128 * AT_STRIDE)   // 4352 floats per 128-k chunk

// LDS pool offsets (floats)
#define OFF_W   0                       // Wlds[640][32] = 20480
#define OFF_A   20480                   // At4[4][AT_CH] = 17408
#define OFF_HC  (OFF_A + 4 * AT_CH)     // hc[1024]
#define OFF_Z1  (OFF_HC + 1024)        // z1s[64]
#define OFF_RED (OFF_Z1 + 64)          // red[128]
#define OFF_BI  (OFF_RED + 128)        // bias[32]
#define POOL_F  (OFF_BI + 32)

__device__ __forceinline__ float waveReduceSum(float v) {
    for (int off = 32; off > 0; off >>= 1) v += __shfl_xor(v, off, 64);
    return v;
}

__device__ __forceinline__ float fast_tanh(float v) {
    float a = fabsf(v);
    float e = __expf(-2.f * a);
    float r = (1.f - e) * __builtin_amdgcn_rcpf(1.f + e);
    return copysignf(r, v);
}

__device__ __forceinline__ float sigmoidf_(float x) {
    return 1.0f / (1.0f + __expf(-x));
}

// Coherent scalar accessors (bypass stale L1/L2; served at IF$).
__device__ __forceinline__ float aload(const float* p) {
    return __hip_atomic_load(p, __ATOMIC_RELAXED, __HIP_MEMORY_SCOPE_AGENT);
}
__device__ __forceinline__ void astore(float* p, float v) {
    __hip_atomic_store(p, v, __ATOMIC_RELAXED, __HIP_MEMORY_SCOPE_AGENT);
}

// Coherent 16B load (async — must waitvm0() before using the result).
__device__ __forceinline__ float4 cload4(const float* p) {
    float4 v;
    asm volatile("global_load_dwordx4 %0, %1, off sc0 sc1" : "=v"(v) : "v"(p));
    return v;
}
__device__ __forceinline__ void waitvm0() {
    asm volatile("s_waitcnt vmcnt(0)" ::: "memory");
}

// ---------------------------------------------------------------------------
__global__ __launch_bounds__(256) void news_kernel(
    const float* __restrict__ in, const float* __restrict__ nW,
    const float* __restrict__ nb, float* __restrict__ x)
{
    int out_idx = blockIdx.x * 4 + (threadIdx.x >> 6);
    int lane = threadIdx.x & 63;
    const float4* src = (const float4*)(in + (size_t)out_idx * E);
    float4 a = src[lane];
    float4 wv = ((const float4*)nW)[lane];
    float s = a.x * wv.x + a.y * wv.y + a.z * wv.z + a.w * wv.w;
    s = waveReduceSum(s);
    if (lane == 0) x[out_idx] = s + nb[0];
}

// ---------------------------------------------------------------------------
__global__ __launch_bounds__(64) void z2_kernel(
    const float* __restrict__ x, const float* __restrict__ A2,
    const float* __restrict__ b2, float* __restrict__ z2)
{
    int b = blockIdx.x >> 7;
    int i = blockIdx.x & 127;
    int s = threadIdx.x;
    __shared__ float xs[T];
    xs[s] = x[((size_t)b * T + s) * IDIM + i];
    __syncthreads();
    float acc = b2[s];
    const float* arow = A2 + s * T;
#pragma unroll 8
    for (int tt = 0; tt < T; ++tt) acc += xs[tt] * arow[tt];
    z2[((size_t)b * IDIM + i) * T + s] = acc;
}

// ---------------------------------------------------------------------------
// Per-quarter two-level barrier: 64 blocks = 8 groups x 8. Hot-poll.
__device__ __forceinline__ void qsync(int* cnt, int q, int ns, int ph) {
    __syncthreads();
    if (threadIdx.x == 0) {
        asm volatile("s_waitcnt vmcnt(0) lgkmcnt(0)" ::: "memory");
        int* subp  = cnt + (q * 8 + (ns >> 3)) * 32;
        int* rootp = cnt + 1024 + q * 32;
        int old = __hip_atomic_fetch_add(subp, 1, __ATOMIC_RELAXED,
                                         __HIP_MEMORY_SCOPE_AGENT);
        if (old == ph * 8 - 1)
            __hip_atomic_fetch_add(rootp, 1, __ATOMIC_RELAXED,
                                   __HIP_MEMORY_SCOPE_AGENT);
        int spins = 0;
        while (__hip_atomic_load(rootp, __ATOMIC_RELAXED,
                                 __HIP_MEMORY_SCOPE_AGENT) < ph * 8) {
            if (++spins > (1 << 16)) break;  // fail visibly, never hang
        }
    }
    __syncthreads();
}

// ---------------------------------------------------------------------------
// Persistent scan. 256 blocks x 512 threads; block bid = q*64 + ns.
// Quarter q owns batches q*32..+32; block handles n-slice ns (8 cols/gate).
// Attention: block pair (2m,2m+1) both compute batch b0+m (dup), write
// disjoint wbuf halves. c-tile lives in registers (block-local dataflow).
__global__ __launch_bounds__(NT, 1) void scan_kernel(
    const float* __restrict__ x, const float* __restrict__ z2,
    const float* __restrict__ A1, const float* __restrict__ b1,
    const float* __restrict__ a3w,
    const float* __restrict__ Wih, const float* __restrict__ Whh,
    const float* __restrict__ bih, const float* __restrict__ bhh,
    float* __restrict__ wbuf, float* __restrict__ hbuf, float* __restrict__ cbuf,
    int* __restrict__ cnt, float* __restrict__ out)
{
    __shared__ float pool[POOL_F];
    float* Wlds = pool + OFF_W;
    float* At4  = pool + OFF_A;
    float* hcs  = pool + OFF_HC;
    float* z1s  = pool + OFF_Z1;
    float* redl = pool + OFF_RED;
    float* blds = pool + OFF_BI;

    const int tid  = threadIdx.x;
    const int bid  = blockIdx.x;
    const int lane = tid & 63, wave = tid >> 6;
    const int q = bid >> 6, ns = bid & 63;
    const int b0 = q * 32, n0 = ns * 8;
    const int ab = b0 + (ns >> 1);             // attn batch (pair-shared)
    const int par = ns & 1;                    // which wbuf half to write
    const int jg = lane & 7, bg = lane >> 3;   // compute tile coords
    const int half = tid >> 8;                 // h-staging: 2 halves x 2 chunks
    const int sbh = (tid & 255) >> 3;          // batch row 0..31
    const int st8 = tid & 7;

    // one-time: weight slice (cols j = g*512 + n0 + nn; 4 gates x 8 n)
    for (int idx = tid; idx < 640 * 32; idx += NT) {
        int jj = idx / 640, k = idx - jj * 640;
        int j = (jj >> 3) * 512 + n0 + (jj & 7);
        Wlds[k * 32 + jj] = (k < 128) ? Wih[(size_t)j * 128 + k]
                                      : Whh[(size_t)j * 512 + (k - 128)];
    }
    if (tid < 32) {
        int j = (tid >> 3) * 512 + n0 + (tid & 7);
        blds[tid] = bih[j] + bhh[j];
    }

    // block-local cell state: thread tid<256 owns c[b0 + (tid>>3)][n0 + (tid&7)]
    float cown = 0.f;

    int ph = 0;
    for (int t = 0; t < T; ++t) {
        // -------- issue coherent h-tile prefetch (latency hides under attn)
        float4 hv[8];
        {
            const float* hrow = hbuf + (size_t)(b0 + sbh) * H + half * 256;
#pragma unroll
            for (int cc = 0; cc < 2; ++cc)
#pragma unroll
                for (int qq = 0; qq < 4; ++qq)
                    hv[cc * 4 + qq] = cload4(hrow + cc * 128 + (st8 + 8 * qq) * 4);
        }

        // -------- phase A: attention (ALL blocks; pair-duplicated) ----------
        {
            hcs[tid]     = aload(hbuf + (size_t)ab * H + tid);
            hcs[H + tid] = aload(cbuf + (size_t)ab * H + tid);
            __syncthreads();
            // z1: scalar stride-64 LDS reads (2-way, conflict-free)
            for (int r = 0; r < 8; ++r) {
                int tt = r * 8 + wave;
                const float* row = A1 + (size_t)tt * (2 * H);
                float p = 0.f;
#pragma unroll
                for (int qq = 0; qq < 16; ++qq)
                    p += row[lane + qq * 64] * hcs[lane + qq * 64];
                p = waveReduceSum(p);
                if (lane == 0) z1s[tt] = p + b1[tt];
            }
            __syncthreads();
            int i = tid >> 2, qt = tid & 3;
            const float* z2r = z2 + ((size_t)ab * IDIM + i) * T + qt * 16;
            const float* z1p = z1s + qt * 16;
            const float* a3p = a3w + qt * 16;
            float accz = 0.f;
#pragma unroll
            for (int qq = 0; qq < 4; ++qq) {
                float4 zv  = *(const float4*)(z2r + qq * 4);
                float4 z1v = *(const float4*)(z1p + qq * 4);
                float4 a3v = *(const float4*)(a3p + qq * 4);
                accz += fast_tanh(z1v.x + zv.x) * a3v.x
                      + fast_tanh(z1v.y + zv.y) * a3v.y
                      + fast_tanh(z1v.z + zv.z) * a3v.z
                      + fast_tanh(z1v.w + zv.w) * a3v.w;
            }
            accz += __shfl_xor(accz, 1, 64);
            accz += __shfl_xor(accz, 2, 64);
            if (qt == 0) redl[i] = accz;
            __syncthreads();
            if (wave == 0) {
                float v0 = redl[lane], v1 = redl[lane + 64];
                float m = fmaxf(v0, v1);
                for (int off = 32; off > 0; off >>= 1)
                    m = fmaxf(m, __shfl_xor(m, off, 64));
                float e0 = __expf(v0 - m), e1 = __expf(v1 - m);
                float inv = 1.0f / waveReduceSum(e0 + e1);
                const float* xt = x + ((size_t)ab * T + t) * IDIM;
                if (par == 0)
                    astore(wbuf + ab * IDIM + lane,      e0 * inv * xt[lane]);
                else
                    astore(wbuf + ab * IDIM + lane + 64, e1 * inv * xt[lane + 64]);
            }
        }

        // -------- stage h-tile into LDS (transposed, stride-34) -------------
        waitvm0();
        {
#pragma unroll
            for (int cc = 0; cc < 2; ++cc)
#pragma unroll
                for (int qq = 0; qq < 4; ++qq) {
                    float4 v = hv[cc * 4 + qq];
                    float* d = At4 + (half * 2 + cc) * AT_CH
                             + ((st8 + 8 * qq) * 4) * AT_STRIDE + sbh;
                    d[0] = v.x; d[AT_STRIDE] = v.y;
                    d[2 * AT_STRIDE] = v.z; d[3 * AT_STRIDE] = v.w;
                }
        }
        __syncthreads();

        // -------- B1: h-part GEMM, wave k-split (64 kk each of 512) ---------
        float acc[4][4];   // [ji (j within group)][eb (b within group)]
#pragma unroll
        for (int a_ = 0; a_ < 4; ++a_)
#pragma unroll
            for (int b_ = 0; b_ < 4; ++b_) acc[a_][b_] = 0.f;
        {
            const float* Ab = At4 + (wave >> 1) * AT_CH
                            + ((wave & 1) * 64) * AT_STRIDE + bg * 4;
            const float* Wb = Wlds + (size_t)(128 + wave * 64) * 32 + jg * 4;
#pragma unroll 8
            for (int i = 0; i < 64; ++i) {
                float4 wv = *(const float4*)(Wb + i * 32);
                float2 a01 = *(const float2*)(Ab + i * AT_STRIDE);
                float2 a23 = *(const float2*)(Ab + i * AT_STRIDE + 2);
                float av[4] = {a01.x, a01.y, a23.x, a23.y};
                const float wj[4] = {wv.x, wv.y, wv.z, wv.w};
#pragma unroll
                for (int a_ = 0; a_ < 4; ++a_)
#pragma unroll
                    for (int b_ = 0; b_ < 4; ++b_)
                        acc[a_][b_] += wj[a_] * av[b_];
            }
        }

        qsync(cnt, q, ns, ++ph);              // wbuf ready (quarter-local)

        // -------- stage w-tile, B2: w-part GEMM (16 kk each of 128) ---------
        {
            const float* wrow = wbuf + (size_t)(b0 + (tid >> 4)) * IDIM;
            float4 w0 = cload4(wrow + (tid & 15) * 4);
            float4 w1 = cload4(wrow + ((tid & 15) + 16) * 4);
            waitvm0();
            int sbw = tid >> 4, st16 = tid & 15;
            float* d0 = At4 + (st16 * 4) * AT_STRIDE + sbw;
            d0[0] = w0.x; d0[AT_STRIDE] = w0.y;
            d0[2 * AT_STRIDE] = w0.z; d0[3 * AT_STRIDE] = w0.w;
            float* d1 = At4 + ((st16 + 16) * 4) * AT_STRIDE + sbw;
            d1[0] = w1.x; d1[AT_STRIDE] = w1.y;
            d1[2 * AT_STRIDE] = w1.z; d1[3 * AT_STRIDE] = w1.w;
        }
        __syncthreads();
        {
            const float* Ab = At4 + (wave * 16) * AT_STRIDE + bg * 4;
            const float* Wb = Wlds + (size_t)(wave * 16) * 32 + jg * 4;
#pragma unroll
            for (int i = 0; i < 16; ++i) {
                float4 wv = *(const float4*)(Wb + i * 32);
                float2 a01 = *(const float2*)(Ab + i * AT_STRIDE);
                float2 a23 = *(const float2*)(Ab + i * AT_STRIDE + 2);
                float av[4] = {a01.x, a01.y, a23.x, a23.y};
                const float wj[4] = {wv.x, wv.y, wv.z, wv.w};
#pragma unroll
                for (int a_ = 0; a_ < 4; ++a_)
#pragma unroll
                    for (int b_ = 0; b_ < 4; ++b_)
                        acc[a_][b_] += wj[a_] * av[b_];
            }
        }

        // -------- 8-way cross-wave k-reduce (stride-33 + jg-rotation) -------
        float* red4 = At4 + AT_CH;            // 8448 floats, chunks 1-2 (dead)
#pragma unroll
        for (int ji = 0; ji < 4; ++ji) {
            int r = jg * 4 + ji;
#pragma unroll
            for (int eb = 0; eb < 4; ++eb)
                red4[wave * 1056 + r * 33 + bg * 4 + ((eb + jg) & 3)] = acc[ji][eb];
        }
        __syncthreads();

        float* glds = At4;                    // chunk 0 (dead after B2)
        if (tid < 256) {
            int jj = tid >> 3, b8 = tid & 7;
            int rot = jj >> 2;
            float bias = blds[jj];
            float s[4] = {bias, bias, bias, bias};
#pragma unroll
            for (int w = 0; w < 8; ++w) {
                const float* rp = red4 + w * 1056 + jj * 33 + b8 * 4;
#pragma unroll
                for (int eb = 0; eb < 4; ++eb)
                    s[eb] += rp[(eb + rot) & 3];
            }
#pragma unroll
            for (int eb = 0; eb < 4; ++eb)
                glds[jj * 33 + b8 * 4 + eb] = s[eb];
        }
        __syncthreads();
        if (tid < 256) {
            int ub = tid >> 3, un = tid & 7;
            float ig = glds[(0 * 8 + un) * 33 + ub];
            float fg = glds[(1 * 8 + un) * 33 + ub];
            float gg = glds[(2 * 8 + un) * 33 + ub];
            float og = glds[(3 * 8 + un) * 33 + ub];
            int gb = b0 + ub, gn = n0 + un;
            float cnew = sigmoidf_(fg) * cown + sigmoidf_(ig) * tanhf(gg);
            float hnew = sigmoidf_(og) * tanhf(cnew);
            cown = cnew;
            astore(cbuf + (size_t)gb * H + gn, cnew);
            astore(hbuf + (size_t)gb * H + gn, hnew);
            out[((size_t)gb * T + t) * H + gn] = hnew;
        }

        qsync(cnt, q, ns, ++ph);              // h_{t+1}, c_{t+1} ready
    }
}

// ---------------------------------------------------------------------------
extern "C" void kernel_launch(void* const* d_in, const int* in_sizes, int n_in,
                              void* d_out, int out_size, void* d_ws, size_t ws_size,
                              hipStream_t stream)
{
    const float* input  = (const float*)d_in[0];
    const float* news_W = (const float*)d_in[1];
    const float* news_b = (const float*)d_in[2];
    const float* A1     = (const float*)d_in[3];
    const float* b1     = (const float*)d_in[4];
    const float* A2     = (const float*)d_in[5];
    const float* b2     = (const float*)d_in[6];
    const float* a3w    = (const float*)d_in[7];
    // d_in[8] = attn3_b: softmax-invariant, unused
    const float* Wih    = (const float*)d_in[9];
    const float* Whh    = (const float*)d_in[10];
    const float* bih    = (const float*)d_in[11];
    const float* bhh    = (const float*)d_in[12];
    float* out = (float*)d_out;

    char* ws = (char*)d_ws;
    size_t off = 0;
    auto alloc = [&](size_t nelem) {
        float* p = (float*)(ws + off);
        off += ((nelem * 4 + 255) / 256) * 256;
        return p;
    };
    float* x    = alloc((size_t)B * T * IDIM);   // 4 MB
    float* z2   = alloc((size_t)B * IDIM * T);   // 4 MB
    float* wbuf = alloc((size_t)B * IDIM);       // 64 KB
    float* hbuf = alloc((size_t)B * H);          // single h buffer
    float* cbuf = alloc((size_t)B * H);          // single c buffer
    int*   cnt  = (int*)alloc(2048);             // barrier counters

    hipMemsetAsync(hbuf, 0, (size_t)B * H * 4, stream);
    hipMemsetAsync(cbuf, 0, (size_t)B * H * 4, stream);
    hipMemsetAsync(cnt, 0, 2048 * 4, stream);

    news_kernel<<<B * T * IDIM / 4, 256, 0, stream>>>(input, news_W, news_b, x);
    z2_kernel<<<B * IDIM, 64, 0, stream>>>(x, A2, b2, z2);
    scan_kernel<<<256, NT, 0, stream>>>(x, z2, A1, b1, a3w, Wih, Whh, bih, bhh,
                                        wbuf, hbuf, cbuf, cnt, out);
}